// Round 8
// baseline (174.927 us; speedup 1.0000x reference)
//
#include <hip/hip_runtime.h>

#define WS 9
#define PS 7
#define KMAX 10
#define STRIDE0 4
#define NEPOCHS 100
#define BB 1
#define TT 5
#define CC 3
#define HH 256
#define WW 256
#define QQ (TT * 64 * 64)             // 20480
#define NOFF 243
#define SELF_IDX 40                   // (WS/2)*WS + WS/2
#define HW (HH * WW)
#define TSTR 20                       // tile row stride: 80B = b128-aligned

typedef float f4a __attribute__((ext_vector_type(4)));              // aligned LDS/reg
typedef float f4u __attribute__((ext_vector_type(4), aligned(4)));  // 4B-aligned global

static __device__ __forceinline__ int k_eff_from_epoch(int ep) {
    int k = (int)((double)KMAX * ((double)(NEPOCHS - ep) / (double)NEPOCHS));
    return k < 2 ? 2 : k;
}

// One query per 256-thread block. Vectorized staging: 540 float4-quads
// (9 planes x 15 rows x 4 quads) via dwordx4 + ds_write_b128; interior planes
// clamp-free (block-uniform). Query patch is read from tile[0] (qpat removed:
// qpat[c][i][j] == tile[0][c][min(hq,4)+i][min(wq,4)+j], bit-exact; wq%4==0
// keeps b128 alignment). Search: 27 groups (dti,dh) x 8 lanes (sub=row i),
// register sliding window over 9 dw + shfl_xor tree. After the post-search
// barrier wave 0 alone does top-k + refine; waves 1-3 exit.
__global__ __launch_bounds__(256) void dnls_query_kernel(
    const float* __restrict__ noisy, const float* __restrict__ deno,
    const float* __restrict__ fflow, const float* __restrict__ bflow,
    const int* __restrict__ ep_ptr, float* __restrict__ partial)
{
    const int q    = blockIdx.x;
    const int tqi  = q >> 12;
    const int r0   = q & 4095;
    const int hq   = (r0 >> 6) * STRIDE0;
    const int wq   = (r0 & 63) * STRIDE0;
    const int tid  = threadIdx.x;
    const int lane = tid & 63;
    const int k_eff = k_eff_from_epoch(ep_ptr[0]);

    __shared__ __align__(16) float tile[3][CC][15][TSTR];   // 10.8 KB
    __shared__ float dpat[CC][PS][8];                       // deno query patch
    __shared__ float dists[256];

    // --- centers (every thread; flow loads are wave-uniform -> broadcast) ---
    const size_t bfo = (size_t)(tqi * 2) * HW + (size_t)hq * WW + wq;
    const int ifdx = (int)rintf(fflow[bfo]);
    const int ifdy = (int)rintf(fflow[bfo + HW]);
    const int ibdx = (int)rintf(bflow[bfo]);
    const int ibdy = (int)rintf(bflow[bfo + HW]);
    const int tc0 = tqi, tc1 = max(tqi - 1, 0), tc2 = min(tqi + 1, TT - 1);
    const int hv0 = hq, hv1 = min(max(hq + ibdy, 0), HH - 1), hv2 = min(max(hq + ifdy, 0), HH - 1);
    const int wv0 = wq, wv1 = min(max(wq + ibdx, 0), WW - 1), wv2 = min(max(wq + ifdx, 0), WW - 1);

    // --- stage tiles: 540 b128 quads (plane p = (dti,c), row, quad) ---
    #pragma unroll
    for (int it = 0; it < 3; ++it) {
        const int u = tid + it * 256;
        if (u < 540) {
            const int p   = u / 60;
            const int rem = u - p * 60;
            const int row = rem >> 2, qd = rem & 3;
            const int dti = (p >= 6) ? 2 : (p >= 3 ? 1 : 0);
            const int c   = p - dti * 3;
            const int tcv = dti == 0 ? tc0 : (dti == 1 ? tc1 : tc2);
            const int hcv = dti == 0 ? hv0 : (dti == 1 ? hv1 : hv2);
            const int wcv = dti == 0 ? wv0 : (dti == 1 ? wv1 : wv2);
            const int h0  = max(hcv - 4, 0), w0 = max(wcv - 4, 0);
            const float* src = noisy + (size_t)(tcv * CC + c) * HW;
            f4a v;
            if (hcv <= HH - 11 && wcv <= WW - 12) {
                // interior plane: rows h0..h0+14 and cols w0..w0+15 all in-bounds
                v = (f4a)(*(const f4u*)(src + (h0 + row) * WW + w0 + qd * 4));
            } else {
                const int rr = min(h0 + row, HH - 1);
                const float* sr = src + rr * WW;
                #pragma unroll
                for (int t = 0; t < 4; ++t) {
                    const int l = qd * 4 + t;
                    v[t] = sr[min(w0 + min(l, 14), WW - 1)];
                }
            }
            *(f4a*)&tile[dti][c][row][qd * 4] = v;
        }
    }
    // --- stage deno query patch (clamps baked in) ---
    if (tid < CC * PS * PS) {
        const int c = tid / 49, ij = tid - c * 49, i = ij / 7, j = ij - (ij / 7) * 7;
        dpat[c][i][j] = deno[(size_t)(tqi * CC + c) * HW
                             + min(hq + i, HH - 1) * WW + min(wq + j, WW - 1)];
    }
    __syncthreads();

    // --- search: group g=(dti,dh), sub = patch row i (sub==7 idle) ---
    {
        const int g = tid >> 3, sub = tid & 7;
        if (g < 27) {
            const int dti = (g >= 18) ? 2 : (g >= 9 ? 1 : 0);
            const int dh  = g - 9 * dti;
            const int hcv = dti == 0 ? hv0 : (dti == 1 ? hv1 : hv2);
            const int wcv = dti == 0 ? wv0 : (dti == 1 ? wv1 : wv2);
            float acc[9];
            #pragma unroll
            for (int dw = 0; dw < 9; ++dw) acc[dw] = 0.f;
            if (sub < PS) {
                const int i  = sub;
                const int oh = min(hq, 4), ow = min(wq, 4);   // query patch inside tile[0]
                float qv[CC][8];
                #pragma unroll
                for (int c = 0; c < CC; ++c) {
                    *(f4a*)&qv[c][0] = *(const f4a*)&tile[0][c][oh + i][ow];
                    *(f4a*)&qv[c][4] = *(const f4a*)&tile[0][c][oh + i][ow + 4];
                }
                if (hcv >= 4 && wcv >= 4) {
                    // fast path: staged clamps are exact; r = dh+i, cols = dw+j
                    const int r = dh + i;
                    #pragma unroll
                    for (int c = 0; c < CC; ++c) {
                        float tv[16];
                        *(f4a*)&tv[0]  = *(const f4a*)&tile[dti][c][r][0];
                        *(f4a*)&tv[4]  = *(const f4a*)&tile[dti][c][r][4];
                        *(f4a*)&tv[8]  = *(const f4a*)&tile[dti][c][r][8];
                        *(f4a*)&tv[12] = *(const f4a*)&tile[dti][c][r][12];
                        #pragma unroll
                        for (int dw = 0; dw < 9; ++dw) {
                            #pragma unroll
                            for (int j = 0; j < 7; ++j) {
                                const float d = qv[c][j] - tv[dw + j];
                                acc[dw] = fmaf(d, d, acc[dw]);
                            }
                        }
                    }
                } else {
                    // top/left-edge centers: double clamp mapped into the tile
                    const int h0 = max(hcv - 4, 0), w0 = max(wcv - 4, 0);
                    const int hc = min(max(hcv + dh - 4, 0), HH - 1);
                    const int r  = min(hc + i, HH - 1) - h0;
                    #pragma unroll
                    for (int c = 0; c < CC; ++c) {
                        #pragma unroll
                        for (int dw = 0; dw < 9; ++dw) {
                            const int wc = min(max(wcv + dw - 4, 0), WW - 1);
                            #pragma unroll
                            for (int j = 0; j < 7; ++j) {
                                const int col = min(wc + j, WW - 1) - w0;
                                const float d = qv[c][j] - tile[dti][c][r][col];
                                acc[dw] = fmaf(d, d, acc[dw]);
                            }
                        }
                    }
                }
            }
            // sum the 7 rows across the 8-lane segment
            #pragma unroll
            for (int dw = 0; dw < 9; ++dw) {
                float v = acc[dw];
                v += __shfl_xor(v, 1);
                v += __shfl_xor(v, 2);
                v += __shfl_xor(v, 4);
                acc[dw] = v;
            }
            if (sub == 0) {
                #pragma unroll
                for (int dw = 0; dw < 9; ++dw) dists[g * 9 + dw] = acc[dw];
            }
        }
    }
    __syncthreads();

    if (tid >= 64) return;   // waves 1-3 done; wave 0 finishes the query

    // --- in-register top-k, wave 0 only (strict <, lowest-index tie-break) ---
    float dv[4]; int dn[4];
    #pragma unroll
    for (int kk = 0; kk < 4; ++kk) {
        const int n = lane + kk * 64;
        float v = (n < NOFF) ? dists[n] : INFINITY;
        if (n == SELF_IDX) v = -INFINITY;
        dv[kk] = v; dn[kk] = n;
    }
    int seln[KMAX];
    #pragma unroll
    for (int k = 0; k < KMAX; ++k) {
        float bv = dv[0]; int bi = dn[0];
        #pragma unroll
        for (int kk = 1; kk < 4; ++kk)
            if (dv[kk] < bv || (dv[kk] == bv && dn[kk] < bi)) { bv = dv[kk]; bi = dn[kk]; }
        #pragma unroll
        for (int off = 32; off > 0; off >>= 1) {
            const float ov = __shfl_xor(bv, off);
            const int   oi = __shfl_xor(bi, off);
            if (ov < bv || (ov == bv && oi < bi)) { bv = ov; bi = oi; }
        }
        seln[k] = bi;
        #pragma unroll
        for (int kk = 0; kk < 4; ++kk) if (dn[kk] == bi) dv[kk] = INFINITY;
    }

    // --- refine: deno-query vs noisy at selected positions (slots 1..k_eff-1) ---
    float part = 0.f;
    const int nref = (k_eff - 1) * 49;
    for (int u = lane; u < nref; u += 64) {
        const int kk = u / 49 + 1;
        const int ij = u - (kk - 1) * 49;
        const int i = ij / 7, j = ij - (ij / 7) * 7;
        int n = seln[1];
        #pragma unroll
        for (int t = 2; t < KMAX; ++t) if (kk == t) n = seln[t];
        const int dti = (n >= 162) ? 2 : (n >= 81 ? 1 : 0);
        const int rr  = n - dti * 81;
        const int dh  = rr / 9;
        const int dw  = rr - dh * 9;
        const int hcv = dti == 0 ? hv0 : (dti == 1 ? hv1 : hv2);
        const int wcv = dti == 0 ? wv0 : (dti == 1 ? wv1 : wv2);
        const int h0  = max(hcv - 4, 0), w0 = max(wcv - 4, 0);
        const int hc  = min(max(hcv + dh - 4, 0), HH - 1);
        const int wc  = min(max(wcv + dw - 4, 0), WW - 1);
        const int row = min(hc + i, HH - 1) - h0;
        const int col = min(wc + j, WW - 1) - w0;
        #pragma unroll
        for (int c = 0; c < CC; ++c) {
            const float d = dpat[c][i][j] - tile[dti][c][row][col];
            part = fmaf(d, d, part);
        }
    }

    #pragma unroll
    for (int off = 32; off > 0; off >>= 1) part += __shfl_xor(part, off);
    if (lane == 0) partial[q] = part;
}

__global__ __launch_bounds__(1024) void dnls_reduce_kernel(
    const float* __restrict__ partial, int n,
    const int* __restrict__ ep_ptr, float* __restrict__ out)
{
    const int tid = threadIdx.x;
    double acc = 0.0;
    for (int i = tid; i < n; i += 1024) acc += (double)partial[i];
    __shared__ double red[1024];
    red[tid] = acc;
    __syncthreads();
    for (int s = 512; s > 0; s >>= 1) {
        if (tid < s) red[tid] += red[tid + s];
        __syncthreads();
    }
    if (tid == 0) {
        const int k_eff = k_eff_from_epoch(ep_ptr[0]);
        out[0] = (float)(red[0] / ((double)n * (double)(k_eff - 1)));
    }
}

extern "C" void kernel_launch(void* const* d_in, const int* in_sizes, int n_in,
                              void* d_out, int out_size, void* d_ws, size_t ws_size,
                              hipStream_t stream) {
    const float* noisy = (const float*)d_in[0];
    const float* deno  = (const float*)d_in[1];
    const float* fflow = (const float*)d_in[2];
    const float* bflow = (const float*)d_in[3];
    const int*   ep    = (const int*)d_in[4];
    float* partial = (float*)d_ws;            // BB*QQ floats = 80 KB
    float* out = (float*)d_out;

    dnls_query_kernel<<<BB * QQ, 256, 0, stream>>>(noisy, deno, fflow, bflow, ep, partial);
    dnls_reduce_kernel<<<1, 1024, 0, stream>>>(partial, BB * QQ, ep, out);
}

// Round 10
// 171.647 us; speedup vs baseline: 1.0191x; 1.0191x over previous
//
#include <hip/hip_runtime.h>

#define WS 9
#define PS 7
#define KMAX 10
#define STRIDE0 4
#define NEPOCHS 100
#define BB 1
#define TT 5
#define CC 3
#define HH 256
#define WW 256
#define QQ (TT * 64 * 64)             // 20480
#define NOFF 243
#define SELF_IDX 40                   // (WS/2)*WS + WS/2
#define HW (HH * WW)
#define TSTR 20                       // tile row stride: 80B = b128-aligned

typedef float f4a __attribute__((ext_vector_type(4)));              // aligned LDS/reg
typedef float f4u __attribute__((ext_vector_type(4), aligned(4)));  // 4B-aligned global

static __device__ __forceinline__ int k_eff_from_epoch(int ep) {
    int k = (int)((double)KMAX * ((double)(NEPOCHS - ep) / (double)NEPOCHS));
    return k < 2 ? 2 : k;
}

// xor1/xor2 within quads via DPP quad_perm (VALU pipe), xor4 via ds_swizzle.
// CTRL must be a constant expression -> template parameter.
template <int CTRL>
static __device__ __forceinline__ float dpp_add(float v) {
    const int x = __float_as_int(v);
    const int y = __builtin_amdgcn_update_dpp(0, x, CTRL, 0xF, 0xF, true);
    return v + __int_as_float(y);
}
static __device__ __forceinline__ float swz4_add(float v) {
    const int x = __float_as_int(v);
    const int y = __builtin_amdgcn_ds_swizzle(x, 0x101F);   // xor-4, and=0x1F
    return v + __int_as_float(y);
}

// One query per 256-thread block (R7 skeleton). Staging: block-uniform switch
// between vectorized 540-quad path (all planes interior; dwordx4+ds_write_b128,
// no clamps) and R7's scalar per-plane path (clamps baked in). Query patch is
// read from tile[0] (qpat[c][i][j] == tile[0][c][min(hq,4)+i][min(wq,4)+j],
// bit-exact). Search: 27 groups (dti,dh) x 8 lanes (sub = patch row i),
// register sliding window over 9 dw; DPP/swizzle tree sums the rows. After the
// post-search barrier wave 0 alone does top-k + refine; waves 1-3 exit.
__global__ __launch_bounds__(256) void dnls_query_kernel(
    const float* __restrict__ noisy, const float* __restrict__ deno,
    const float* __restrict__ fflow, const float* __restrict__ bflow,
    const int* __restrict__ ep_ptr, float* __restrict__ partial)
{
    const int q    = blockIdx.x;
    const int tqi  = q >> 12;
    const int r0   = q & 4095;
    const int hq   = (r0 >> 6) * STRIDE0;
    const int wq   = (r0 & 63) * STRIDE0;
    const int tid  = threadIdx.x;
    const int lane = tid & 63;
    const int k_eff = k_eff_from_epoch(ep_ptr[0]);

    __shared__ __align__(16) float tile[3][CC][15][TSTR];   // 10.8 KB
    __shared__ float dpat[CC][PS][8];                       // deno query patch
    __shared__ float dists[256];

    // --- centers (every thread; flow loads are wave-uniform -> broadcast) ---
    const size_t bfo = (size_t)(tqi * 2) * HW + (size_t)hq * WW + wq;
    const int ifdx = (int)rintf(fflow[bfo]);
    const int ifdy = (int)rintf(fflow[bfo + HW]);
    const int ibdx = (int)rintf(bflow[bfo]);
    const int ibdy = (int)rintf(bflow[bfo + HW]);
    const int tc0 = tqi, tc1 = max(tqi - 1, 0), tc2 = min(tqi + 1, TT - 1);
    const int hv0 = hq, hv1 = min(max(hq + ibdy, 0), HH - 1), hv2 = min(max(hq + ifdy, 0), HH - 1);
    const int wv0 = wq, wv1 = min(max(wq + ibdx, 0), WW - 1), wv2 = min(max(wq + ifdx, 0), WW - 1);

    // --- staging: block-uniform interior test ---
    const bool allint = (hv0 <= HH - 11) & (wv0 <= WW - 12) &
                        (hv1 <= HH - 11) & (wv1 <= WW - 12) &
                        (hv2 <= HH - 11) & (wv2 <= WW - 12);
    if (allint) {
        // vectorized: 540 b128 quads (plane p=(dti,c), row, quad), zero clamps
        #pragma unroll
        for (int it = 0; it < 3; ++it) {
            const int u = tid + it * 256;
            if (u < 540) {
                const int p   = u / 60;
                const int rem = u - p * 60;
                const int row = rem >> 2, qd = rem & 3;
                const int dti = (p >= 6) ? 2 : (p >= 3 ? 1 : 0);
                const int c   = p - dti * 3;
                const int tcv = dti == 0 ? tc0 : (dti == 1 ? tc1 : tc2);
                const int hcv = dti == 0 ? hv0 : (dti == 1 ? hv1 : hv2);
                const int wcv = dti == 0 ? wv0 : (dti == 1 ? wv1 : wv2);
                const int h0  = max(hcv - 4, 0), w0 = max(wcv - 4, 0);
                const float* src = noisy + (size_t)(tcv * CC + c) * HW;
                *(f4a*)&tile[dti][c][row][qd * 4] =
                    (f4a)(*(const f4u*)(src + (h0 + row) * WW + w0 + qd * 4));
            }
        }
    } else {
        // scalar per-plane path (R7): clamps baked in, uniform branch per plane
        #pragma unroll
        for (int dtc = 0; dtc < 9; ++dtc) {
            const int dti = dtc / 3, c = dtc % 3;          // compile-time
            if (tid < 225) {
                const int row = tid / 15;
                const int col = tid - row * 15;
                const int tcv = dti == 0 ? tc0 : (dti == 1 ? tc1 : tc2);
                const int hcv = dti == 0 ? hv0 : (dti == 1 ? hv1 : hv2);
                const int wcv = dti == 0 ? wv0 : (dti == 1 ? wv1 : wv2);
                const int h0 = max(hcv - 4, 0), w0 = max(wcv - 4, 0);
                const float* src = noisy + (size_t)(tcv * CC + c) * HW;
                tile[dti][c][row][col] =
                    src[min(h0 + row, HH - 1) * WW + min(w0 + col, WW - 1)];
            }
        }
    }
    // --- stage deno query patch (clamps baked in) ---
    if (tid < CC * PS * PS) {
        const int c = tid / 49, ij = tid - c * 49, i = ij / 7, j = ij - (ij / 7) * 7;
        dpat[c][i][j] = deno[(size_t)(tqi * CC + c) * HW
                             + min(hq + i, HH - 1) * WW + min(wq + j, WW - 1)];
    }
    __syncthreads();

    // --- search: group g=(dti,dh), sub = patch row i (sub==7 idle) ---
    {
        const int g = tid >> 3, sub = tid & 7;
        if (g < 27) {
            const int dti = (g >= 18) ? 2 : (g >= 9 ? 1 : 0);
            const int dh  = g - 9 * dti;
            const int hcv = dti == 0 ? hv0 : (dti == 1 ? hv1 : hv2);
            const int wcv = dti == 0 ? wv0 : (dti == 1 ? wv1 : wv2);
            float acc[9];
            #pragma unroll
            for (int dw = 0; dw < 9; ++dw) acc[dw] = 0.f;
            if (sub < PS) {
                const int i  = sub;
                const int oh = min(hq, 4), ow = min(wq, 4);   // query patch inside tile[0]
                float qv[CC][8];
                #pragma unroll
                for (int c = 0; c < CC; ++c) {
                    *(f4a*)&qv[c][0] = *(const f4a*)&tile[0][c][oh + i][ow];
                    *(f4a*)&qv[c][4] = *(const f4a*)&tile[0][c][oh + i][ow + 4];
                }
                if (hcv >= 4 && wcv >= 4) {
                    // fast path: staged clamps are exact; r = dh+i, cols = dw+j
                    const int r = dh + i;
                    #pragma unroll
                    for (int c = 0; c < CC; ++c) {
                        float tv[16];
                        *(f4a*)&tv[0]  = *(const f4a*)&tile[dti][c][r][0];
                        *(f4a*)&tv[4]  = *(const f4a*)&tile[dti][c][r][4];
                        *(f4a*)&tv[8]  = *(const f4a*)&tile[dti][c][r][8];
                        *(f4a*)&tv[12] = *(const f4a*)&tile[dti][c][r][12];
                        #pragma unroll
                        for (int dw = 0; dw < 9; ++dw) {
                            #pragma unroll
                            for (int j = 0; j < 7; ++j) {
                                const float d = qv[c][j] - tv[dw + j];
                                acc[dw] = fmaf(d, d, acc[dw]);
                            }
                        }
                    }
                } else {
                    // top/left-edge centers: double clamp mapped into the tile
                    const int h0 = max(hcv - 4, 0), w0 = max(wcv - 4, 0);
                    const int hc = min(max(hcv + dh - 4, 0), HH - 1);
                    const int r  = min(hc + i, HH - 1) - h0;
                    #pragma unroll
                    for (int c = 0; c < CC; ++c) {
                        #pragma unroll
                        for (int dw = 0; dw < 9; ++dw) {
                            const int wc = min(max(wcv + dw - 4, 0), WW - 1);
                            #pragma unroll
                            for (int j = 0; j < 7; ++j) {
                                const int col = min(wc + j, WW - 1) - w0;
                                const float d = qv[c][j] - tile[dti][c][r][col];
                                acc[dw] = fmaf(d, d, acc[dw]);
                            }
                        }
                    }
                }
            }
            // sum the 7 rows across the 8-lane segment: xor1,xor2 via DPP
            // quad_perm (VALU pipe), xor4 via ds_swizzle; same tree shape as
            // __shfl_xor -> bit-identical sums.
            #pragma unroll
            for (int dw = 0; dw < 9; ++dw) {
                float v = acc[dw];
                v = dpp_add<0xB1>(v);   // quad_perm [1,0,3,2] : xor 1
                v = dpp_add<0x4E>(v);   // quad_perm [2,3,0,1] : xor 2
                v = swz4_add(v);        // xor 4 within 8-lane group
                acc[dw] = v;
            }
            if (sub == 0) {
                #pragma unroll
                for (int dw = 0; dw < 9; ++dw) dists[g * 9 + dw] = acc[dw];
            }
        }
    }
    __syncthreads();

    if (tid >= 64) return;   // waves 1-3 done; wave 0 finishes the query

    // --- in-register top-k, wave 0 only (strict <, lowest-index tie-break) ---
    float dv[4]; int dn[4];
    #pragma unroll
    for (int kk = 0; kk < 4; ++kk) {
        const int n = lane + kk * 64;
        float v = (n < NOFF) ? dists[n] : INFINITY;
        if (n == SELF_IDX) v = -INFINITY;
        dv[kk] = v; dn[kk] = n;
    }
    int seln[KMAX];
    #pragma unroll
    for (int k = 0; k < KMAX; ++k) {
        float bv = dv[0]; int bi = dn[0];
        #pragma unroll
        for (int kk = 1; kk < 4; ++kk)
            if (dv[kk] < bv || (dv[kk] == bv && dn[kk] < bi)) { bv = dv[kk]; bi = dn[kk]; }
        #pragma unroll
        for (int off = 32; off > 0; off >>= 1) {
            const float ov = __shfl_xor(bv, off);
            const int   oi = __shfl_xor(bi, off);
            if (ov < bv || (ov == bv && oi < bi)) { bv = ov; bi = oi; }
        }
        seln[k] = bi;
        #pragma unroll
        for (int kk = 0; kk < 4; ++kk) if (dn[kk] == bi) dv[kk] = INFINITY;
    }

    // --- refine: deno-query vs noisy at selected positions (slots 1..k_eff-1) ---
    float part = 0.f;
    const int nref = (k_eff - 1) * 49;
    for (int u = lane; u < nref; u += 64) {
        const int kk = u / 49 + 1;
        const int ij = u - (kk - 1) * 49;
        const int i = ij / 7, j = ij - (ij / 7) * 7;
        int n = seln[1];
        #pragma unroll
        for (int t = 2; t < KMAX; ++t) if (kk == t) n = seln[t];
        const int dti = (n >= 162) ? 2 : (n >= 81 ? 1 : 0);
        const int rr  = n - dti * 81;
        const int dh  = rr / 9;
        const int dw  = rr - dh * 9;
        const int hcv = dti == 0 ? hv0 : (dti == 1 ? hv1 : hv2);
        const int wcv = dti == 0 ? wv0 : (dti == 1 ? wv1 : wv2);
        const int h0  = max(hcv - 4, 0), w0 = max(wcv - 4, 0);
        const int hc  = min(max(hcv + dh - 4, 0), HH - 1);
        const int wc  = min(max(wcv + dw - 4, 0), WW - 1);
        const int row = min(hc + i, HH - 1) - h0;
        const int col = min(wc + j, WW - 1) - w0;
        #pragma unroll
        for (int c = 0; c < CC; ++c) {
            const float d = dpat[c][i][j] - tile[dti][c][row][col];
            part = fmaf(d, d, part);
        }
    }

    #pragma unroll
    for (int off = 32; off > 0; off >>= 1) part += __shfl_xor(part, off);
    if (lane == 0) partial[q] = part;
}

__global__ __launch_bounds__(1024) void dnls_reduce_kernel(
    const float* __restrict__ partial, int n,
    const int* __restrict__ ep_ptr, float* __restrict__ out)
{
    const int tid = threadIdx.x;
    double acc = 0.0;
    for (int i = tid; i < n; i += 1024) acc += (double)partial[i];
    __shared__ double red[1024];
    red[tid] = acc;
    __syncthreads();
    for (int s = 512; s > 0; s >>= 1) {
        if (tid < s) red[tid] += red[tid + s];
        __syncthreads();
    }
    if (tid == 0) {
        const int k_eff = k_eff_from_epoch(ep_ptr[0]);
        out[0] = (float)(red[0] / ((double)n * (double)(k_eff - 1)));
    }
}

extern "C" void kernel_launch(void* const* d_in, const int* in_sizes, int n_in,
                              void* d_out, int out_size, void* d_ws, size_t ws_size,
                              hipStream_t stream) {
    const float* noisy = (const float*)d_in[0];
    const float* deno  = (const float*)d_in[1];
    const float* fflow = (const float*)d_in[2];
    const float* bflow = (const float*)d_in[3];
    const int*   ep    = (const int*)d_in[4];
    float* partial = (float*)d_ws;            // BB*QQ floats = 80 KB
    float* out = (float*)d_out;

    dnls_query_kernel<<<BB * QQ, 256, 0, stream>>>(noisy, deno, fflow, bflow, ep, partial);
    dnls_reduce_kernel<<<1, 1024, 0, stream>>>(partial, BB * QQ, ep, out);
}